// Round 10
// baseline (924.783 us; speedup 1.0000x reference)
//
#include <hip/hip_runtime.h>
#include <cstddef>

#define TTT   20
#define GRIDN 400       // 25600 / (4 waves * 16 seqs)
#define BLOCK 256       // 4 INDEPENDENT waves (no loop barriers)
#define LDSB  152576    // 114688 WF + 32768 ST + 5120 SC

typedef __attribute__((ext_vector_type(8))) _Float16 f16x8;
typedef __attribute__((ext_vector_type(4))) _Float16 f16x4;
typedef __attribute__((ext_vector_type(4))) float    f32x4;

struct BF { f16x8 hi, lo; };

// global row -> weight fragment (lane supplies W[row][kbase + (lane>>4)*8 + j])
__device__ __forceinline__ BF load_bf(const float* rowp, int lane) {
  BF fr;
  const float* p = rowp + ((lane >> 4) << 3);
  float t[8];
  *(float4*)&t[0] = *(const float4*)(p);
  *(float4*)&t[4] = *(const float4*)(p + 4);
#pragma unroll
  for (int jj = 0; jj < 8; ++jj) {
    const _Float16 h = (_Float16)t[jj];
    fr.hi[jj] = h;
    fr.lo[jj] = (_Float16)(t[jj] - (float)h);
  }
  return fr;
}

// bilinear 3-term: Wh*Sh + Wl*Sh + Wh*Sl  (weights as A operand, state as B)
__device__ __forceinline__ f32x4 mfma3w(f16x8 wh, f16x8 wl, f16x8 sh, f16x8 sl, f32x4 c) {
  c = __builtin_amdgcn_mfma_f32_16x16x32_f16(wh, sh, c, 0, 0, 0);
  c = __builtin_amdgcn_mfma_f32_16x16x32_f16(wl, sh, c, 0, 0, 0);
  c = __builtin_amdgcn_mfma_f32_16x16x32_f16(wh, sl, c, 0, 0, 0);
  return c;
}

__global__ void __launch_bounds__(BLOCK, 1) gat_gru_v5(
    const int*   __restrict__ g_inputs,
    const int*   __restrict__ g_nseq,
    const int*   __restrict__ g_nmask,
    const float* __restrict__ g_emb,
    const float* __restrict__ g_wih,   // (192,128)
    const float* __restrict__ g_whh,   // (192,64)
    const float* __restrict__ g_bih,
    const float* __restrict__ g_bhh,
    const float* __restrict__ g_aw1,   // (64,128)
    const float* __restrict__ g_ab1,
    const float* __restrict__ g_aw2,
    float*       __restrict__ g_out)
{
  extern __shared__ char smem[];
  _Float16* WF = (_Float16*)smem;             // [56 frags][2 planes][512]
  _Float16* ST = WF + 56 * 1024;              // [4 waves][2 planes][2048]
  float*    SCb = (float*)(smem + 147456);    // [4 waves][16 seq][20 t]

  const int tid  = threadIdx.x;
  const int lane = tid & 63;
  const int w    = tid >> 6;
  const int l15  = lane & 15;     // seq (B-frag col / C col)
  const int g    = lane >> 4;
  const int seqq = lane >> 2;     // gather role: seq 0..15
  const int part = lane & 3;      //              64B quarter of the row
  const int gseq0 = blockIdx.x * 64 + w * 16;
  const int gseq  = gseq0 + seqq;

  _Float16* SThi = ST + w * 4096;
  _Float16* STlo = SThi + 2048;
  float*    SCw  = SCb + w * 320;

  // ================= cooperative weight-fragment staging (once) =================
  // frag id: kt0/1: fid = kt*16 + gate*4 + tile (gate 0=r,1=z,2=nh,3=at)
  //          kt2/3: fid = 32 + (kt-2)*12 + gate*4 + tile (gate 0=r,1=z,2=nx)
  for (int u = tid; u < 3584; u += BLOCK) {
    const int fid  = u >> 6;
    const int slot = u & 63;
    const int sl15 = slot & 15, sg = slot >> 4;
    int kt, gi, tile;
    if (fid < 32) { kt = fid >> 4; gi = (fid >> 2) & 3; tile = fid & 3; }
    else { const int r2 = fid - 32; kt = 2 + (r2 >= 12); gi = (r2 % 12) >> 2; tile = r2 & 3; }
    const int f = tile * 16 + sl15;
    const float* src;
    if (kt < 2) {                        // h-part k 0..63
      const int kc = kt * 32 + sg * 8;
      if (gi == 0)      src = g_whh + (size_t)f * 64 + kc;
      else if (gi == 1) src = g_whh + (size_t)(64 + f) * 64 + kc;
      else if (gi == 2) src = g_whh + (size_t)(128 + f) * 64 + kc;
      else              src = g_aw1 + (size_t)f * 128 + kc;
    } else {                             // nb-part k 64..127 -> cols 0..63
      const int kc = (kt - 2) * 32 + sg * 8;
      if (gi == 0)      src = g_wih + (size_t)f * 128 + kc;
      else if (gi == 1) src = g_wih + (size_t)(64 + f) * 128 + kc;
      else              src = g_wih + (size_t)(128 + f) * 128 + kc;
    }
    float t8[8];
    *(float4*)&t8[0] = *(const float4*)(src);
    *(float4*)&t8[4] = *(const float4*)(src + 4);
    f16x8 hi, lo;
#pragma unroll
    for (int jj = 0; jj < 8; ++jj) {
      const _Float16 h = (_Float16)t8[jj];
      hi[jj] = h; lo[jj] = (_Float16)(t8[jj] - (float)h);
    }
    *(f16x8*)&WF[fid * 1024 + slot * 8]       = hi;
    *(f16x8*)&WF[fid * 1024 + 512 + slot * 8] = lo;
  }

  // ================= per-wave setup (no cross-wave deps) =================
  // central embedding: gather + normalize + stage into state h-slot (k 0..63)
  f32x4 cva[4];
  {
    const int ci = g_inputs[gseq];
    const float* cp = g_emb + (size_t)ci * 64 + part * 16;
#pragma unroll
    for (int i = 0; i < 4; ++i) cva[i] = *(const f32x4*)(cp + i * 4);
    float ss = 0.f;
#pragma unroll
    for (int i = 0; i < 4; ++i)
#pragma unroll
      for (int q = 0; q < 4; ++q) ss += cva[i][q] * cva[i][q];
    ss += __shfl_xor(ss, 1, 64); ss += __shfl_xor(ss, 2, 64);
    const float inv = 1.f / fmaxf(sqrtf(ss), 1e-12f);
#pragma unroll
    for (int i = 0; i < 4; ++i) {
      f16x4 h4, l4;
#pragma unroll
      for (int q = 0; q < 4; ++q) {
        const float v = cva[i][q] * inv;
        const _Float16 hh = (_Float16)v;
        h4[q] = hh; l4[q] = (_Float16)(v - (float)hh);
      }
      const int e = ((part * 2 + (i >> 1)) * 16 + seqq) * 8 + (i & 1) * 4;
      *(f16x4*)&SThi[e] = h4;
      *(f16x4*)&STlo[e] = l4;
    }
  }
  asm volatile("" ::: "memory");

  // phase-0: cst = cent-contribution + biases (per lane: seq=l15, f=t*16+g*4+q)
  f32x4 cr[4], cz[4], cnh[4], cnx[4], cat[4], w24[4];
#pragma unroll
  for (int t = 0; t < 4; ++t)
#pragma unroll
    for (int q = 0; q < 4; ++q) { cr[t][q]=0.f; cz[t][q]=0.f; cnx[t][q]=0.f; cat[t][q]=0.f; }
#pragma unroll
  for (int k2 = 0; k2 < 2; ++k2) {
    const f16x8 sh = *(const f16x8*)&SThi[k2 * 512 + lane * 8];
    const f16x8 sl = *(const f16x8*)&STlo[k2 * 512 + lane * 8];
#pragma unroll
    for (int t = 0; t < 4; ++t) {
      BF b;
      b = load_bf(g_wih + (size_t)(t*16 + l15) * 128 + 64 + k2*32, lane);
      cr[t]  = mfma3w(b.hi, b.lo, sh, sl, cr[t]);
      b = load_bf(g_wih + (size_t)(64 + t*16 + l15) * 128 + 64 + k2*32, lane);
      cz[t]  = mfma3w(b.hi, b.lo, sh, sl, cz[t]);
      b = load_bf(g_wih + (size_t)(128 + t*16 + l15) * 128 + 64 + k2*32, lane);
      cnx[t] = mfma3w(b.hi, b.lo, sh, sl, cnx[t]);
      b = load_bf(g_aw1 + (size_t)(t*16 + l15) * 128 + 64 + k2*32, lane);
      cat[t] = mfma3w(b.hi, b.lo, sh, sl, cat[t]);
    }
  }
#pragma unroll
  for (int t = 0; t < 4; ++t) {
    const int f0 = t * 16 + g * 4;
    const f32x4 br1 = *(const f32x4*)(g_bih + f0),       br2 = *(const f32x4*)(g_bhh + f0);
    const f32x4 bz1 = *(const f32x4*)(g_bih + 64 + f0),  bz2 = *(const f32x4*)(g_bhh + 64 + f0);
    cnh[t] = *(const f32x4*)(g_bhh + 128 + f0);
    const f32x4 bn1 = *(const f32x4*)(g_bih + 128 + f0);
    const f32x4 ba  = *(const f32x4*)(g_ab1 + f0);
    w24[t] = *(const f32x4*)(g_aw2 + f0);
#pragma unroll
    for (int q = 0; q < 4; ++q) {
      cr[t][q] += br1[q] + br2[q];
      cz[t][q] += bz1[q] + bz2[q];
      cnx[t][q] += bn1[q];
      cat[t][q] += ba[q];
    }
  }
  asm volatile("" ::: "memory");

  // stage nb_0 into state k 64..127 (h-slot left stale: it=0 skips h MFMAs)
  {
    const int idx0 = g_nseq[(size_t)gseq * TTT];
    const float* rp = g_emb + (size_t)idx0 * 64 + part * 16;
#pragma unroll
    for (int i = 0; i < 4; ++i) {
      const f32x4 v4 = *(const f32x4*)(rp + i * 4);
      f16x4 h4, l4;
#pragma unroll
      for (int q = 0; q < 4; ++q) {
        const _Float16 hh = (_Float16)v4[q];
        h4[q] = hh; l4[q] = (_Float16)(v4[q] - (float)hh);
      }
      const int e = ((8 + part * 2 + (i >> 1)) * 16 + seqq) * 8 + (i & 1) * 4;
      *(f16x4*)&SThi[e] = h4;
      *(f16x4*)&STlo[e] = l4;
    }
  }
  f32x4 hp[4];
#pragma unroll
  for (int t = 0; t < 4; ++t)
#pragma unroll
    for (int q = 0; q < 4; ++q) hp[t][q] = 0.f;

  __syncthreads();   // the ONLY block barrier: WF staging complete

  auto ldw = [&](int fid, f16x8& wh, f16x8& wl) {
    wh = *(const f16x8*)&WF[fid * 1024 + lane * 8];
    wl = *(const f16x8*)&WF[fid * 1024 + 512 + lane * 8];
  };

  // ================= recurrent loop: ZERO barriers =================
#pragma unroll 1
  for (int it = 0; it <= TTT; ++it) {
    const bool full = (it < TTT);
    const bool dog  = (it < TTT - 1);
    f32x4 nbv[4];
    if (dog) {                              // prefetch nb_{it+1}
      const int idx = g_nseq[(size_t)gseq * TTT + it + 1];
      const float* rp = g_emb + (size_t)idx * 64 + part * 16;
#pragma unroll
      for (int i = 0; i < 4; ++i) nbv[i] = *(const f32x4*)(rp + i * 4);
    }
    f32x4 ar[4], az[4], anh[4], anx[4], aat[4];
#pragma unroll
    for (int t = 0; t < 4; ++t) {
      aat[t] = cat[t];
      if (full) { ar[t]=cr[t]; az[t]=cz[t]; anh[t]=cnh[t]; anx[t]=cnx[t]; }
    }
    if (it >= 1) {                          // h-part (k 0..63)
#pragma unroll
      for (int k2 = 0; k2 < 2; ++k2) {
        const f16x8 sh = *(const f16x8*)&SThi[k2 * 512 + lane * 8];
        const f16x8 sl = *(const f16x8*)&STlo[k2 * 512 + lane * 8];
#pragma unroll
        for (int t = 0; t < 4; ++t) {
          f16x8 wh, wl;
          ldw(k2*16 + 12 + t, wh, wl); aat[t] = mfma3w(wh, wl, sh, sl, aat[t]);
          if (full) {
            ldw(k2*16 + t,     wh, wl); ar[t]  = mfma3w(wh, wl, sh, sl, ar[t]);
            ldw(k2*16 + 4 + t, wh, wl); az[t]  = mfma3w(wh, wl, sh, sl, az[t]);
            ldw(k2*16 + 8 + t, wh, wl); anh[t] = mfma3w(wh, wl, sh, sl, anh[t]);
          }
        }
      }
    }
    if (full) {                             // nb-part (k 64..127)
#pragma unroll
      for (int k2 = 0; k2 < 2; ++k2) {
        const f16x8 sh = *(const f16x8*)&SThi[(2 + k2) * 512 + lane * 8];
        const f16x8 sl = *(const f16x8*)&STlo[(2 + k2) * 512 + lane * 8];
#pragma unroll
        for (int t = 0; t < 4; ++t) {
          f16x8 wh, wl;
          ldw(32 + k2*12 + t,     wh, wl); ar[t]  = mfma3w(wh, wl, sh, sl, ar[t]);
          ldw(32 + k2*12 + 4 + t, wh, wl); az[t]  = mfma3w(wh, wl, sh, sl, az[t]);
          ldw(32 + k2*12 + 8 + t, wh, wl); anx[t] = mfma3w(wh, wl, sh, sl, anx[t]);
        }
      }
    }
    asm volatile("" ::: "memory");          // all state reads before any state write

    if (it >= 1) {                          // score for gru_out[it-1]
      float p = 0.f;
#pragma unroll
      for (int t = 0; t < 4; ++t)
#pragma unroll
        for (int q = 0; q < 4; ++q) {
          const float a = aat[t][q];
          p += w24[t][q] * (a > 0.f ? a : 0.2f * a);
        }
      p += __shfl_xor(p, 16, 64);
      p += __shfl_xor(p, 32, 64);
      if (g == 0) SCw[l15 * TTT + (it - 1)] = p;
    }
    if (full) {                             // GRU pointwise, in-lane; write h
#pragma unroll
      for (int t = 0; t < 4; ++t) {
        f16x4 h4, l4;
#pragma unroll
        for (int q = 0; q < 4; ++q) {
          const float r  = 1.f / (1.f + __expf(-ar[t][q]));
          const float zz = 1.f / (1.f + __expf(-az[t][q]));
          const float u  = __expf(2.f * (anx[t][q] + r * anh[t][q]));
          const float n  = 1.f - 2.f / (u + 1.f);   // NaN-safe tanh
          const float hnew = (1.f - zz) * n + zz * hp[t][q];
          hp[t][q] = hnew;
          const _Float16 hh = (_Float16)hnew;
          h4[q] = hh; l4[q] = (_Float16)(hnew - (float)hh);
        }
        const int eh = ((t * 2 + (g >> 1)) * 16 + l15) * 8 + (g & 1) * 4;
        *(f16x4*)&SThi[eh] = h4;
        *(f16x4*)&STlo[eh] = l4;
      }
      if (dog) {                            // store prefetched nb_{it+1}
#pragma unroll
        for (int i = 0; i < 4; ++i) {
          f16x4 h4, l4;
#pragma unroll
          for (int q = 0; q < 4; ++q) {
            const _Float16 hh = (_Float16)nbv[i][q];
            h4[q] = hh; l4[q] = (_Float16)(nbv[i][q] - (float)hh);
          }
          const int e = ((8 + part * 2 + (i >> 1)) * 16 + seqq) * 8 + (i & 1) * 4;
          *(f16x4*)&SThi[e] = h4;
          *(f16x4*)&STlo[e] = l4;
        }
      }
    }
    asm volatile("" ::: "memory");          // writes before next-iter reads
  }

  // ================= per-wave epilogue: softmax + z =================
  {
    int mbits = 0;
    float mx = -1e30f;
#pragma unroll
    for (int t = 0; t < TTT; ++t) {
      if (g_nmask[(size_t)gseq * TTT + t]) {
        mbits |= (1 << t);
        mx = fmaxf(mx, SCw[seqq * TTT + t]);
      }
    }
    float sum = 0.f;
    f32x4 za[4];
#pragma unroll
    for (int i = 0; i < 4; ++i)
#pragma unroll
      for (int q = 0; q < 4; ++q) za[i][q] = 0.f;
    for (int t = 0; t < TTT; ++t) {
      if (mbits & (1 << t)) {
        const float e = __expf(SCw[seqq * TTT + t] - mx);
        sum += e;
        const int idx = g_nseq[(size_t)gseq * TTT + t];
        const float* rp = g_emb + (size_t)idx * 64 + part * 16;
#pragma unroll
        for (int i = 0; i < 4; ++i) {
          const f32x4 e4 = *(const f32x4*)(rp + i * 4);
#pragma unroll
          for (int q = 0; q < 4; ++q) za[i][q] += e * e4[q];
        }
      }
    }
    f32x4 o[4];
    if (mbits) {
      const float inv = 1.f / sum;
#pragma unroll
      for (int i = 0; i < 4; ++i)
#pragma unroll
        for (int q = 0; q < 4; ++q) o[i][q] = za[i][q] * inv;
    } else {
      // fallback: normalized central (re-gather; rare)
      const int ci = g_inputs[gseq];
      const float* cp = g_emb + (size_t)ci * 64 + part * 16;
      float ss = 0.f;
#pragma unroll
      for (int i = 0; i < 4; ++i) {
        o[i] = *(const f32x4*)(cp + i * 4);
#pragma unroll
        for (int q = 0; q < 4; ++q) ss += o[i][q] * o[i][q];
      }
      ss += __shfl_xor(ss, 1, 64); ss += __shfl_xor(ss, 2, 64);
      const float inv = 1.f / fmaxf(sqrtf(ss), 1e-12f);
#pragma unroll
      for (int i = 0; i < 4; ++i)
#pragma unroll
        for (int q = 0; q < 4; ++q) o[i][q] *= inv;
    }
    float* op = g_out + (size_t)gseq * 64 + part * 16;
#pragma unroll
    for (int i = 0; i < 4; ++i) *(f32x4*)(op + i * 4) = o[i];
  }
}

extern "C" void kernel_launch(void* const* d_in, const int* in_sizes, int n_in,
                              void* d_out, int out_size, void* d_ws, size_t ws_size,
                              hipStream_t stream) {
  (void)in_sizes; (void)n_in; (void)out_size; (void)d_ws; (void)ws_size;
  (void)hipFuncSetAttribute((const void*)gat_gru_v5,
                            hipFuncAttributeMaxDynamicSharedMemorySize, LDSB);
  gat_gru_v5<<<GRIDN, BLOCK, LDSB, stream>>>(
      (const int*)d_in[0], (const int*)d_in[1], (const int*)d_in[2],
      (const float*)d_in[3], (const float*)d_in[4], (const float*)d_in[5],
      (const float*)d_in[6], (const float*)d_in[7], (const float*)d_in[8],
      (const float*)d_in[9], (const float*)d_in[10],
      (float*)d_out);
}

// Round 11
// 739.191 us; speedup vs baseline: 1.2511x; 1.2511x over previous
//
#include <hip/hip_runtime.h>
#include <cstddef>

#define TTT   20
#define SBLK  16
#define GRIDN 1600      // 25600/16
#define BLOCK 256       // 4 waves

typedef __attribute__((ext_vector_type(8))) _Float16 f16x8;
typedef __attribute__((ext_vector_type(4))) _Float16 f16x4;
typedef __attribute__((ext_vector_type(4))) float    f32x4;

struct BF { f16x8 hi, lo; };

// B fragment: lane provides B[k][n=f] = W[f][k], k = kbase + (lane>>4)*8 + j
__device__ __forceinline__ BF load_bf(const float* rowp, int lane) {
  BF fr;
  const float* p = rowp + ((lane >> 4) << 3);
  float t[8];
  *(float4*)&t[0] = *(const float4*)(p);
  *(float4*)&t[4] = *(const float4*)(p + 4);
#pragma unroll
  for (int jj = 0; jj < 8; ++jj) {
    const _Float16 h = (_Float16)t[jj];
    fr.hi[jj] = h;
    fr.lo[jj] = (_Float16)(t[jj] - (float)h);
  }
  return fr;
}

// bilinear 3-term split: AhBh + AhBl + AlBh  (~f32-grade)
__device__ __forceinline__ f32x4 mfma3(f16x8 ah, f16x8 al, const BF& b, f32x4 c) {
  c = __builtin_amdgcn_mfma_f32_16x16x32_f16(ah, b.hi, c, 0, 0, 0);
  c = __builtin_amdgcn_mfma_f32_16x16x32_f16(ah, b.lo, c, 0, 0, 0);
  c = __builtin_amdgcn_mfma_f32_16x16x32_f16(al, b.hi, c, 0, 0, 0);
  return c;
}

__global__ void __launch_bounds__(BLOCK, 2) gat_gru_v6(
    const int*   __restrict__ g_inputs,
    const int*   __restrict__ g_nseq,
    const int*   __restrict__ g_nmask,
    const float* __restrict__ g_emb,
    const float* __restrict__ g_wih,   // (192,128)
    const float* __restrict__ g_whh,   // (192,64)
    const float* __restrict__ g_bih,
    const float* __restrict__ g_bhh,
    const float* __restrict__ g_aw1,   // (64,128)
    const float* __restrict__ g_ab1,
    const float* __restrict__ g_aw2,
    float*       __restrict__ g_out)
{
  // A in MFMA-fragment order: elem((k,row)) = ((k>>3)*16 + row)*8 + (k&7)
  // -> a wave's A-frag read (ks) is a CONTIGUOUS 1KB region (conflict-free).
  __shared__ _Float16 AFhi[2][2048];     // 2 buffers x 16 rows x 128 k
  __shared__ _Float16 AFlo[2][2048];
  __shared__ float    SCP[TTT * 4 * 16]; // [t][wave][seq] score partials
  __shared__ float    SC2[16 * TTT];     // [s][t] masked scores
  __shared__ float    BB [16 * TTT];     // [s][t] betas
  __shared__ float    HN [16 * 64];      // normalized central
  __shared__ int      HAS[16];

  const int tid  = threadIdx.x;
  const int lane = tid & 63;
  const int w    = tid >> 6;
  const int s    = tid >> 4;          // gather/pointwise role: seq 0..15
  const int j    = tid & 15;          //                        col group
  const int g    = lane >> 4;
  const int f    = w * 16 + (lane & 15);   // this lane's feature column
  const int sbase = blockIdx.x * SBLK;
  const size_t snb = (size_t)(sbase + s) * TTT;

  // ---- early global loads ----
  const int ci = g_inputs[sbase + s];
  const float4 cent0 = *(const float4*)(g_emb + (size_t)ci * 64 + j * 4);
  const int idx0 = g_nseq[snb];
  const float4 nb0 = *(const float4*)(g_emb + (size_t)idx0 * 64 + j * 4);

  const float w2f  = g_aw2[f];
  const float bihr = g_bih[f], bihz = g_bih[64 + f], bihn = g_bih[128 + f];
  const float bhhr = g_bhh[f], bhhz = g_bhh[64 + f], bhhn = g_bhh[128 + f];
  const float ab1f = g_ab1[f];

  // ---- phase-0 B fragments (central columns 64..127) ----
  BF B0r[2], B0z[2], B0nx[2], B0at[2];
#pragma unroll
  for (int k2 = 0; k2 < 2; ++k2) {
    B0r[k2]  = load_bf(g_wih + (size_t)f * 128         + 64 + k2 * 32, lane);
    B0z[k2]  = load_bf(g_wih + (size_t)(64 + f) * 128  + 64 + k2 * 32, lane);
    B0nx[k2] = load_bf(g_wih + (size_t)(128 + f) * 128 + 64 + k2 * 32, lane);
    B0at[k2] = load_bf(g_aw1 + (size_t)f * 128         + 64 + k2 * 32, lane);
  }

  // ---- normalize central embedding, stage into AF[0] h-slot ----
  {
    float hv4[4] = {cent0.x, cent0.y, cent0.z, cent0.w};
    float ssum = hv4[0]*hv4[0] + hv4[1]*hv4[1] + hv4[2]*hv4[2] + hv4[3]*hv4[3];
    ssum += __shfl_xor(ssum, 1, 64); ssum += __shfl_xor(ssum, 2, 64);
    ssum += __shfl_xor(ssum, 4, 64); ssum += __shfl_xor(ssum, 8, 64);
    const float inv = 1.f / fmaxf(sqrtf(ssum), 1e-12f);
#pragma unroll
    for (int c = 0; c < 4; ++c) hv4[c] *= inv;
    *(float4*)&HN[s * 64 + j * 4] = *(float4*)hv4;
    const int k0 = 4 * j;
    const int e  = ((k0 >> 3) * 16 + s) * 8 + (k0 & 7);
    f16x4 hi, lo;
#pragma unroll
    for (int c = 0; c < 4; ++c) {
      hi[c] = (_Float16)hv4[c];
      lo[c] = (_Float16)(hv4[c] - (float)hi[c]);
    }
    *(f16x4*)&AFhi[0][e] = hi;
    *(f16x4*)&AFlo[0][e] = lo;
  }
  __syncthreads();

  // ---- phase-0 matmul -> per-lane constants (central contrib + biases) ----
  f32x4 cr, cz, cnx, cat;
  float cnh_s;               // nh const is per-feature scalar (bhhn) only
  {
    f32x4 a_r, a_z, a_nx, a_at;
#pragma unroll
    for (int q = 0; q < 4; ++q) { a_r[q] = 0.f; a_z[q] = 0.f; a_nx[q] = 0.f; a_at[q] = 0.f; }
#pragma unroll
    for (int k2 = 0; k2 < 2; ++k2) {
      const f16x8 ah = *(const f16x8*)&AFhi[0][k2 * 512 + lane * 8];
      const f16x8 al = *(const f16x8*)&AFlo[0][k2 * 512 + lane * 8];
      a_r  = mfma3(ah, al, B0r[k2],  a_r);
      a_z  = mfma3(ah, al, B0z[k2],  a_z);
      a_nx = mfma3(ah, al, B0nx[k2], a_nx);
      a_at = mfma3(ah, al, B0at[k2], a_at);
    }
#pragma unroll
    for (int q = 0; q < 4; ++q) {
      cr[q]  = a_r[q]  + bihr + bhhr;
      cz[q]  = a_z[q]  + bihz + bhhz;
      cnx[q] = a_nx[q] + bihn;
      cat[q] = a_at[q] + ab1f;
    }
    cnh_s = bhhn;
  }

  // ---- stage AF[1]: h_{-1}=0 and nb_0 ----
  {
    const int k0 = 4 * j;
    const int e  = ((k0 >> 3) * 16 + s) * 8 + (k0 & 7);
    f16x4 z4;
#pragma unroll
    for (int c = 0; c < 4; ++c) z4[c] = (_Float16)0.f;
    *(f16x4*)&AFhi[1][e] = z4;
    *(f16x4*)&AFlo[1][e] = z4;
    const int k1 = 64 + 4 * j;
    const int e1 = ((k1 >> 3) * 16 + s) * 8 + (k1 & 7);
    float tv[4] = {nb0.x, nb0.y, nb0.z, nb0.w};
    f16x4 hi, lo;
#pragma unroll
    for (int c = 0; c < 4; ++c) {
      hi[c] = (_Float16)tv[c];
      lo[c] = (_Float16)(tv[c] - (float)hi[c]);
    }
    *(f16x4*)&AFhi[1][e1] = hi;
    *(f16x4*)&AFlo[1][e1] = lo;
  }

  // ---- main-loop B fragments (held in registers for the whole loop) ----
  BF Br[4], Bz[4], Bnh[2], Bnx[2], Bat[2];
#pragma unroll
  for (int k2 = 0; k2 < 2; ++k2) {
    Br[k2]     = load_bf(g_whh + (size_t)f * 64          + k2 * 32, lane);
    Br[2 + k2] = load_bf(g_wih + (size_t)f * 128         + k2 * 32, lane);
    Bz[k2]     = load_bf(g_whh + (size_t)(64 + f) * 64   + k2 * 32, lane);
    Bz[2 + k2] = load_bf(g_wih + (size_t)(64 + f) * 128  + k2 * 32, lane);
    Bnh[k2]    = load_bf(g_whh + (size_t)(128 + f) * 64  + k2 * 32, lane);
    Bnx[k2]    = load_bf(g_wih + (size_t)(128 + f) * 128 + k2 * 32, lane);
    Bat[k2]    = load_bf(g_aw1 + (size_t)f * 128         + k2 * 32, lane);
  }
  float hp[4] = {0.f, 0.f, 0.f, 0.f};
  f32x4 patt;                      // deferred attn pre-activation (prev iter)
#pragma unroll
  for (int q = 0; q < 4; ++q) patt[q] = 0.f;

  // 2-deep nb prefetch: nbHold = nb_{it+1}, loaded one FULL iteration early
  // (HBM gather ~900cy now covered by a whole iteration, not just the MFMA
  //  phase -> removes the vmcnt stall before the ds_write + barrier).
  float4 nbHold;
  {
    const int idx1 = g_nseq[snb + 1];
    nbHold = *(const float4*)(g_emb + (size_t)idx1 * 64 + j * 4);
  }
  __syncthreads();

  // ============ recurrent loop: ONE barrier per iteration ============
  for (int it = 0; it <= TTT; ++it) {
    const int rd  = (it + 1) & 1;
    const int wrb = it & 1;
    const bool full = (it < TTT);
    const bool dog  = (it < TTT - 1);

    // issue next-next nb gather FIRST (consumed next iteration)
    float4 nbNext;
    if (it <= TTT - 3) {
      const int idx = g_nseq[snb + it + 2];
      nbNext = *(const float4*)(g_emb + (size_t)idx * 64 + j * 4);
    }

    // deferred score reduce for t = it-2 (off the barrier-critical path)
    if (it >= 2) {
      float c0, c1, c2, c3;
      {
        float a;
        a = patt[0]; c0 = w2f * (a > 0.f ? a : 0.2f * a);
        a = patt[1]; c1 = w2f * (a > 0.f ? a : 0.2f * a);
        a = patt[2]; c2 = w2f * (a > 0.f ? a : 0.2f * a);
        a = patt[3]; c3 = w2f * (a > 0.f ? a : 0.2f * a);
      }
#pragma unroll
      for (int m = 1; m < 16; m <<= 1) {
        c0 += __shfl_xor(c0, m, 64); c1 += __shfl_xor(c1, m, 64);
        c2 += __shfl_xor(c2, m, 64); c3 += __shfl_xor(c3, m, 64);
      }
      if ((lane & 15) == 0) {
        float4 pv; pv.x = c0; pv.y = c1; pv.z = c2; pv.w = c3;
        *(float4*)&SCP[((it - 2) * 4 + w) * 16 + g * 4] = pv;
      }
    }

    f32x4 ar = cr, az = cz, anx = cnx, aat = cat, anh;
#pragma unroll
    for (int q = 0; q < 4; ++q) anh[q] = cnh_s;
#pragma unroll
    for (int k2 = 0; k2 < 2; ++k2) {   // h-part (k 0..63)
      const f16x8 ah = *(const f16x8*)&AFhi[rd][k2 * 512 + lane * 8];
      const f16x8 al = *(const f16x8*)&AFlo[rd][k2 * 512 + lane * 8];
      aat = mfma3(ah, al, Bat[k2], aat);
      if (full) {
        ar  = mfma3(ah, al, Br[k2],  ar);
        az  = mfma3(ah, al, Bz[k2],  az);
        anh = mfma3(ah, al, Bnh[k2], anh);
      }
    }
    if (full) {
#pragma unroll
      for (int k2 = 0; k2 < 2; ++k2) { // nb-part (k 64..127)
        const f16x8 ah = *(const f16x8*)&AFhi[rd][(2 + k2) * 512 + lane * 8];
        const f16x8 al = *(const f16x8*)&AFlo[rd][(2 + k2) * 512 + lane * 8];
        ar  = mfma3(ah, al, Br[2 + k2], ar);
        az  = mfma3(ah, al, Bz[2 + k2], az);
        anx = mfma3(ah, al, Bnx[k2],    anx);
      }
    }
    if (it >= 1) patt = aat;         // stash for next-iter (or post-loop) reduce

    if (full) {
      // GRU pointwise FIRST (h-write is the barrier-critical chain)
      const int kc = f >> 3, fb = f & 7;
#pragma unroll
      for (int q = 0; q < 4; ++q) {
        const float r  = 1.f / (1.f + __expf(-ar[q]));
        const float zz = 1.f / (1.f + __expf(-az[q]));
        const float u  = __expf(2.f * (anx[q] + r * anh[q]));
        const float n  = 1.f - 2.f / (u + 1.f);      // NaN-safe tanh
        const float hnew = (1.f - zz) * n + zz * hp[q];
        hp[q] = hnew;
        const _Float16 hh = (_Float16)hnew;
        const int e = (kc * 16 + g * 4 + q) * 8 + fb;
        AFhi[wrb][e] = hh;
        AFlo[wrb][e] = (_Float16)(hnew - (float)hh);
      }
      if (dog) {
        // store nbHold = nb_{it+1} (loaded LAST iteration -> latency covered)
        const int k1 = 64 + 4 * j;
        const int e1 = ((k1 >> 3) * 16 + s) * 8 + (k1 & 7);
        float tv[4] = {nbHold.x, nbHold.y, nbHold.z, nbHold.w};
        f16x4 hi, lo;
#pragma unroll
        for (int c = 0; c < 4; ++c) {
          hi[c] = (_Float16)tv[c];
          lo[c] = (_Float16)(tv[c] - (float)hi[c]);
        }
        *(f16x4*)&AFhi[wrb][e1] = hi;
        *(f16x4*)&AFlo[wrb][e1] = lo;
      }
      nbHold = nbNext;
    }
    __syncthreads();
  }

  // post-loop: reduce the final score (t = TTT-1, stashed at it = TTT)
  {
    float c0, c1, c2, c3;
    {
      float a;
      a = patt[0]; c0 = w2f * (a > 0.f ? a : 0.2f * a);
      a = patt[1]; c1 = w2f * (a > 0.f ? a : 0.2f * a);
      a = patt[2]; c2 = w2f * (a > 0.f ? a : 0.2f * a);
      a = patt[3]; c3 = w2f * (a > 0.f ? a : 0.2f * a);
    }
#pragma unroll
    for (int m = 1; m < 16; m <<= 1) {
      c0 += __shfl_xor(c0, m, 64); c1 += __shfl_xor(c1, m, 64);
      c2 += __shfl_xor(c2, m, 64); c3 += __shfl_xor(c3, m, 64);
    }
    if ((lane & 15) == 0) {
      float4 pv; pv.x = c0; pv.y = c1; pv.z = c2; pv.w = c3;
      *(float4*)&SCP[((TTT - 1) * 4 + w) * 16 + g * 4] = pv;
    }
  }
  __syncthreads();

  // ================== epilogue ==================
  // E1: combine 4 wave-partials per score, apply mask
  {
    const int s1 = tid & 15, t0 = tid >> 4;
#pragma unroll
    for (int rep = 0; rep < 2; ++rep) {
      const int t = t0 + rep * 16;
      if (t < TTT) {
        const float sc = SCP[t * 64 + s1] + SCP[t * 64 + 16 + s1] +
                         SCP[t * 64 + 32 + s1] + SCP[t * 64 + 48 + s1];
        const int mk = g_nmask[(size_t)(sbase + s1) * TTT + t];
        SC2[s1 * TTT + t] = mk ? sc : -1e30f;
      }
    }
  }
  __syncthreads();
  // E2: per-seq softmax over 20 (16 threads per seq)
  {
    const float v0 = SC2[s * TTT + j];
    const float v1 = (j < 4) ? SC2[s * TTT + 16 + j] : -1e30f;
    float mx = fmaxf(v0, v1);
#pragma unroll
    for (int m = 1; m < 16; m <<= 1) mx = fmaxf(mx, __shfl_xor(mx, m, 64));
    const float e0 = (v0 > -1e29f) ? __expf(v0 - mx) : 0.f;
    const float e1 = (v1 > -1e29f) ? __expf(v1 - mx) : 0.f;
    float sm = e0 + e1;
#pragma unroll
    for (int m = 1; m < 16; m <<= 1) sm += __shfl_xor(sm, m, 64);
    const float rinv = (sm > 0.f) ? 1.f / sm : 0.f;
    BB[s * TTT + j] = e0 * rinv;
    if (j < 4) BB[s * TTT + 16 + j] = e1 * rinv;
    if (j == 0) HAS[s] = (sm > 0.f) ? 1 : 0;
  }
  __syncthreads();
  // E3: z = sum_t beta_t * nb_t  (coalesced 256B row re-gather)
  {
    float za[4] = {0.f, 0.f, 0.f, 0.f};
    for (int t = 0; t < TTT; ++t) {
      const float b = BB[s * TTT + t];
      if (b != 0.f) {
        const int idx = g_nseq[snb + t];
        const float4 e4 = *(const float4*)(g_emb + (size_t)idx * 64 + j * 4);
        za[0] += b * e4.x; za[1] += b * e4.y; za[2] += b * e4.z; za[3] += b * e4.w;
      }
    }
    float4 o;
    if (HAS[s]) { o.x = za[0]; o.y = za[1]; o.z = za[2]; o.w = za[3]; }
    else        { o = *(float4*)&HN[s * 64 + j * 4]; }
    *(float4*)(g_out + (size_t)(sbase + s) * 64 + j * 4) = o;
  }
}

extern "C" void kernel_launch(void* const* d_in, const int* in_sizes, int n_in,
                              void* d_out, int out_size, void* d_ws, size_t ws_size,
                              hipStream_t stream) {
  (void)in_sizes; (void)n_in; (void)out_size; (void)d_ws; (void)ws_size;
  gat_gru_v6<<<GRIDN, BLOCK, 0, stream>>>(
      (const int*)d_in[0], (const int*)d_in[1], (const int*)d_in[2],
      (const float*)d_in[3], (const float*)d_in[4], (const float*)d_in[5],
      (const float*)d_in[6], (const float*)d_in[7], (const float*)d_in[8],
      (const float*)d_in[9], (const float*)d_in[10],
      (float*)d_out);
}